// Round 2
// baseline (3827.758 us; speedup 1.0000x reference)
//
#include <hip/hip_runtime.h>

// APPNP link-prediction: N=100000 nodes, F=256 in, H=128 hidden,
// E=1.6M edges, K=10 hops x 2 layers, alpha=0.1, decode over 800K edges.
// All fp32. Strategy: build CSR-by-dst once per call, gather-only SpMV hops.
// Index inputs may arrive as int32 (harness converts) or int64 (reference
// dtype) -> on-device dtype probe + uniform branch.

constexpr int Hd = 128;       // hidden dim
constexpr int Fin = 256;      // input feature dim
constexpr float A_ = 0.1f;    // alpha
constexpr float OMA = 0.9f;   // 1 - alpha

__device__ __forceinline__ int idx_at(const void* p, size_t i, int is64) {
    if (is64) return (int)((const long long*)p)[i];
    return ((const int*)p)[i];
}

// ---------------- dtype probe ----------------
// int64 little-endian with values < 2^31 => every odd 32-bit word is 0.
// int32 random indices => odd words are index values, ~never all zero.
__global__ void k_detect(const int* __restrict__ p, int npairs, int* __restrict__ flag) {
    __shared__ int any32;
    if (threadIdx.x == 0) any32 = 0;
    __syncthreads();
    for (int i = threadIdx.x; i < npairs; i += blockDim.x)
        if (p[2 * i + 1] != 0) any32 = 1;
    __syncthreads();
    if (threadIdx.x == 0) *flag = any32 ? 0 : 1;   // 1 => int64
}

// ---------------- preprocessing ----------------

__global__ void k_zero_i32(int* __restrict__ p, int n) {
    int i = blockIdx.x * blockDim.x + threadIdx.x;
    if (i < n) p[i] = 0;
}

__global__ void k_count(const void* __restrict__ ei, int E, int* __restrict__ cnt,
                        const int* __restrict__ flag) {
    int is64 = *flag;
    int e = blockIdx.x * blockDim.x + threadIdx.x;
    if (e < E) {
        int d = idx_at(ei, (size_t)E + e, is64);   // edge_index[1][e]
        atomicAdd(&cnt[d], 1);
    }
}

__global__ void k_dinv(const int* __restrict__ cnt, float* __restrict__ dinv, int N) {
    int i = blockIdx.x * blockDim.x + threadIdx.x;
    if (i < N) dinv[i] = rsqrtf((float)(cnt[i] + 1));  // +1 self-loop, deg >= 1
}

// exclusive scan of cnt -> rp, 256-per-block; bsum[b] = block total
__global__ void k_scan1(const int* __restrict__ cnt, int* __restrict__ rp,
                        int* __restrict__ bsum, int N) {
    __shared__ int s[256];
    int t = threadIdx.x;
    int i = blockIdx.x * 256 + t;
    int v = (i < N) ? cnt[i] : 0;
    s[t] = v;
    __syncthreads();
    for (int off = 1; off < 256; off <<= 1) {
        int add = (t >= off) ? s[t - off] : 0;
        __syncthreads();
        s[t] += add;
        __syncthreads();
    }
    if (i < N) rp[i] = s[t] - v;
    if (t == 255) bsum[blockIdx.x] = s[255];
}

// single-block exclusive scan of bsum (nb <= 512)
__global__ void k_scan2(int* __restrict__ bsum, int nb) {
    __shared__ int s[512];
    int t = threadIdx.x;
    int v = (t < nb) ? bsum[t] : 0;
    s[t] = v;
    __syncthreads();
    for (int off = 1; off < 512; off <<= 1) {
        int add = (t >= off) ? s[t - off] : 0;
        __syncthreads();
        s[t] += add;
        __syncthreads();
    }
    if (t < nb) bsum[t] = s[t] - v;
}

__global__ void k_scan3(int* __restrict__ rp, const int* __restrict__ bsum,
                        int* __restrict__ cursor, int N, int E) {
    int i = blockIdx.x * blockDim.x + threadIdx.x;
    if (i < N) {
        rp[i] += bsum[i >> 8];
        cursor[i] = 0;
    }
    if (i == 0) rp[N] = E;
}

__global__ void k_place(const void* __restrict__ ei, int E,
                        const int* __restrict__ rp, int* __restrict__ cursor,
                        const float* __restrict__ dinv,
                        int* __restrict__ col, float* __restrict__ w,
                        const int* __restrict__ flag) {
    int is64 = *flag;
    int e = blockIdx.x * blockDim.x + threadIdx.x;
    if (e < E) {
        int s = idx_at(ei, (size_t)e, is64);
        int d = idx_at(ei, (size_t)E + e, is64);
        int p = atomicAdd(&cursor[d], 1);
        int idx = rp[d] + p;
        col[idx] = s;
        w[idx] = dinv[s] * dinv[d];
    }
}

// ---------------- GEMM: C[N][128] = act(A)[N][KTOT] @ B[KTOT][128] ----------------

template <int KTOT, bool RELU>
__global__ __launch_bounds__(256) void k_gemm(const float* __restrict__ A,
                                              const float* __restrict__ B,
                                              float* __restrict__ C, int N) {
    __shared__ float As[64][36];    // pad 36: 16B-aligned rows, 2-way-max bank alias
    __shared__ float Bs[32][128];
    const int t  = threadIdx.x;
    const int tx = t & 15;          // col group: 8 cols each
    const int ty = t >> 4;          // row group: 4 rows each
    const int r0 = blockIdx.x * 64;

    float acc[4][8];
#pragma unroll
    for (int i = 0; i < 4; ++i)
#pragma unroll
        for (int j = 0; j < 8; ++j) acc[i][j] = 0.f;

    for (int k0 = 0; k0 < KTOT; k0 += 32) {
        // A tile 64x32
#pragma unroll
        for (int p = 0; p < 2; ++p) {
            int row = p * 32 + (t >> 3);
            int kk  = (t & 7) * 4;
            int gr  = r0 + row;
            float4 v = make_float4(0.f, 0.f, 0.f, 0.f);
            if (gr < N) v = *(const float4*)&A[(size_t)gr * KTOT + k0 + kk];
            if (RELU) {
                v.x = fmaxf(v.x, 0.f); v.y = fmaxf(v.y, 0.f);
                v.z = fmaxf(v.z, 0.f); v.w = fmaxf(v.w, 0.f);
            }
            *(float4*)&As[row][kk] = v;
        }
        // B tile 32x128
#pragma unroll
        for (int p = 0; p < 4; ++p) {
            int kr = p * 8 + (t >> 5);
            int c  = (t & 31) * 4;
            *(float4*)&Bs[kr][c] = *(const float4*)&B[(size_t)(k0 + kr) * Hd + c];
        }
        __syncthreads();
#pragma unroll
        for (int kk = 0; kk < 32; ++kk) {
            float a[4];
#pragma unroll
            for (int i = 0; i < 4; ++i) a[i] = As[ty * 4 + i][kk];
            float4 b0 = *(const float4*)&Bs[kk][tx * 8];
            float4 b1 = *(const float4*)&Bs[kk][tx * 8 + 4];
            float b[8] = {b0.x, b0.y, b0.z, b0.w, b1.x, b1.y, b1.z, b1.w};
#pragma unroll
            for (int i = 0; i < 4; ++i)
#pragma unroll
                for (int j = 0; j < 8; ++j) acc[i][j] = fmaf(a[i], b[j], acc[i][j]);
        }
        __syncthreads();
    }
#pragma unroll
    for (int i = 0; i < 4; ++i) {
        int gr = r0 + ty * 4 + i;
        if (gr < N) {
            *(float4*)&C[(size_t)gr * Hd + tx * 8]     = make_float4(acc[i][0], acc[i][1], acc[i][2], acc[i][3]);
            *(float4*)&C[(size_t)gr * Hd + tx * 8 + 4] = make_float4(acc[i][4], acc[i][5], acc[i][6], acc[i][7]);
        }
    }
}

// ---------------- propagation hop: zout = 0.9*(A_hat @ zin) + 0.1*h ----------------
// wave-per-node; lane holds float2 of the 128 features; CSR gather, no atomics.

__global__ __launch_bounds__(256) void k_hop(const float* __restrict__ zin,
                                             const float* __restrict__ h,
                                             float* __restrict__ zout,
                                             const int* __restrict__ rp,
                                             const int* __restrict__ col,
                                             const float* __restrict__ w,
                                             const float* __restrict__ dinv, int N) {
    int wid  = (blockIdx.x * blockDim.x + threadIdx.x) >> 6;
    int lane = threadIdx.x & 63;
    if (wid >= N) return;
    const int i = wid;
    const int f = lane * 2;
    float di = dinv[i];
    float2 zi = *(const float2*)&zin[(size_t)i * Hd + f];
    float accx = di * di * zi.x;
    float accy = di * di * zi.y;
    int e = rp[i], end = rp[i + 1];
    for (; e < end; ++e) {
        int s   = col[e];
        float we = w[e];
        float2 zv = *(const float2*)&zin[(size_t)s * Hd + f];
        accx = fmaf(we, zv.x, accx);
        accy = fmaf(we, zv.y, accy);
    }
    float2 hh = *(const float2*)&h[(size_t)i * Hd + f];
    float2 o;
    o.x = OMA * accx + A_ * hh.x;
    o.y = OMA * accy + A_ * hh.y;
    *(float2*)&zout[(size_t)i * Hd + f] = o;
}

// ---------------- decode: out[j] = dot(z[e0[j]], z[e1[j]]) ----------------
// 16 lanes per edge, float4 loads, shfl_xor reduce within 16.

__global__ __launch_bounds__(256) void k_decode(const float* __restrict__ z,
                                                const void* __restrict__ pos,
                                                const void* __restrict__ neg,
                                                float* __restrict__ out, int P, int Q,
                                                const int* __restrict__ flag) {
    int is64 = *flag;
    int t   = blockIdx.x * blockDim.x + threadIdx.x;
    int j   = t >> 4;
    int sub = t & 15;
    if (j >= P + Q) return;
    int a, b;
    if (j < P) { a = idx_at(pos, (size_t)j, is64); b = idx_at(pos, (size_t)P + j, is64); }
    else       { int jj = j - P; a = idx_at(neg, (size_t)jj, is64); b = idx_at(neg, (size_t)Q + jj, is64); }
    const float4* za = (const float4*)&z[(size_t)a * Hd];
    const float4* zb = (const float4*)&z[(size_t)b * Hd];
    float s = 0.f;
#pragma unroll
    for (int q = 0; q < 2; ++q) {
        float4 va = za[q * 16 + sub];
        float4 vb = zb[q * 16 + sub];
        s += va.x * vb.x + va.y * vb.y + va.z * vb.z + va.w * vb.w;
    }
#pragma unroll
    for (int off = 8; off >= 1; off >>= 1) s += __shfl_xor(s, off, 16);
    if (sub == 0) out[j] = s;
}

// ---------------- launch ----------------

extern "C" void kernel_launch(void* const* d_in, const int* in_sizes, int n_in,
                              void* d_out, int out_size, void* d_ws, size_t ws_size,
                              hipStream_t stream) {
    const float* x   = (const float*)d_in[0];
    const void*  ei  = d_in[1];
    const void*  pos = d_in[2];
    const void*  neg = d_in[3];
    const float* W1  = (const float*)d_in[4];
    const float* W2  = (const float*)d_in[5];
    float*       out = (float*)d_out;

    const int N = in_sizes[0] / Fin;
    const int E = in_sizes[1] / 2;
    const int P = in_sizes[2] / 2;
    const int Q = in_sizes[3] / 2;

    // workspace carve-up (all re-initialized every call)
    char*  ws  = (char*)d_ws;
    size_t off = 0;
    auto carve = [&](size_t bytes) -> void* {
        void* p = ws + off;
        off = (off + bytes + 511) & ~(size_t)511;
        return p;
    };
    float* h      = (float*)carve((size_t)N * Hd * 4);
    float* zA     = (float*)carve((size_t)N * Hd * 4);
    float* zB     = (float*)carve((size_t)N * Hd * 4);
    float* dinv   = (float*)carve((size_t)N * 4);
    int*   cnt    = (int*)carve((size_t)N * 4);
    int*   rp     = (int*)carve((size_t)(N + 1) * 4);
    int*   cursor = (int*)carve((size_t)N * 4);
    int*   col    = (int*)carve((size_t)E * 4);
    float* w      = (float*)carve((size_t)E * 4);
    int    nb     = (N + 255) / 256;
    int*   bsum   = (int*)carve((size_t)nb * 4);
    int*   flag   = (int*)carve(4);
    (void)ws_size;

    const int gN = (N + 255) / 256;
    const int gE = (E + 255) / 256;

    // ---- dtype probe + build CSR by dst + norms ----
    k_detect<<<1, 256, 0, stream>>>((const int*)ei, 4096, flag);
    k_zero_i32<<<gN, 256, 0, stream>>>(cnt, N);
    k_count<<<gE, 256, 0, stream>>>(ei, E, cnt, flag);
    k_dinv<<<gN, 256, 0, stream>>>(cnt, dinv, N);
    k_scan1<<<nb, 256, 0, stream>>>(cnt, rp, bsum, N);
    k_scan2<<<1, 512, 0, stream>>>(bsum, nb);
    k_scan3<<<gN, 256, 0, stream>>>(rp, bsum, cursor, N, E);
    k_place<<<gE, 256, 0, stream>>>(ei, E, rp, cursor, dinv, col, w, flag);

    const int gGemm = (N + 63) / 64;
    const int gHop  = (N * 64 + 255) / 256;

    // ---- layer 1: h = x @ W1; 10 hops ----
    k_gemm<Fin, false><<<gGemm, 256, 0, stream>>>(x, W1, h, N);
    {
        float* bufs[2] = {zA, zB};
        const float* zin = h;
        for (int k = 0; k < 10; ++k) {
            float* zout = bufs[k & 1];
            k_hop<<<gHop, 256, 0, stream>>>(zin, h, zout, rp, col, w, dinv, N);
            zin = zout;
        }
    }
    // final layer-1 z is in zB (k=9 -> bufs[1])

    // ---- layer 2: h = relu(zB) @ W2; 10 hops ----
    k_gemm<Hd, true><<<gGemm, 256, 0, stream>>>(zB, W2, h, N);
    {
        float* bufs[2] = {zA, zB};
        const float* zin = h;
        for (int k = 0; k < 10; ++k) {
            float* zout = bufs[k & 1];
            k_hop<<<gHop, 256, 0, stream>>>(zin, h, zout, rp, col, w, dinv, N);
            zin = zout;
        }
    }
    // final z in zB

    // ---- decode ----
    const int gDec = ((P + Q) * 16 + 255) / 256;
    k_decode<<<gDec, 256, 0, stream>>>(zB, pos, neg, out, P, Q, flag);
}

// Round 3
// 2925.462 us; speedup vs baseline: 1.3084x; 1.3084x over previous
//
#include <hip/hip_runtime.h>

// APPNP link-prediction: N=100000 nodes, F=256 in, H=128 hidden,
// E=1.6M edges, K=10 hops x 2 layers, alpha=0.1, decode over 800K edges.
// All fp32. CSR-by-dst (self-loops folded in, 0.9*norm pre-folded into w),
// gather-only SpMV hops with 8-wide MLP unroll.

constexpr int Hd = 128;       // hidden dim
constexpr int Fin = 256;      // input feature dim
constexpr float A_ = 0.1f;    // alpha
constexpr float OMA = 0.9f;   // 1 - alpha

__device__ __forceinline__ int idx_at(const void* p, size_t i, int is64) {
    if (is64) return (int)((const long long*)p)[i];
    return ((const int*)p)[i];
}

// ---------------- dtype probe ----------------
// int64 little-endian with values < 2^31 => every odd 32-bit word is 0.
__global__ void k_detect(const int* __restrict__ p, int npairs, int* __restrict__ flag) {
    __shared__ int any32;
    if (threadIdx.x == 0) any32 = 0;
    __syncthreads();
    for (int i = threadIdx.x; i < npairs; i += blockDim.x)
        if (p[2 * i + 1] != 0) any32 = 1;
    __syncthreads();
    if (threadIdx.x == 0) *flag = any32 ? 0 : 1;   // 1 => int64
}

// ---------------- preprocessing ----------------

__global__ void k_zero_i32(int* __restrict__ p, int n) {
    int i = blockIdx.x * blockDim.x + threadIdx.x;
    if (i < n) p[i] = 0;
}

__global__ void k_count(const void* __restrict__ ei, int E, int* __restrict__ cnt,
                        const int* __restrict__ flag) {
    int is64 = *flag;
    int e = blockIdx.x * blockDim.x + threadIdx.x;
    if (e < E) {
        int d = idx_at(ei, (size_t)E + e, is64);   // edge_index[1][e]
        atomicAdd(&cnt[d], 1);
    }
}

__global__ void k_dinv(const int* __restrict__ cnt, float* __restrict__ dinv, int N) {
    int i = blockIdx.x * blockDim.x + threadIdx.x;
    if (i < N) dinv[i] = rsqrtf((float)(cnt[i] + 1));  // +1 self-loop
}

// exclusive scan of (cnt+1) -> rp (row = in-edges + self-loop)
__global__ void k_scan1(const int* __restrict__ cnt, int* __restrict__ rp,
                        int* __restrict__ bsum, int N) {
    __shared__ int s[256];
    int t = threadIdx.x;
    int i = blockIdx.x * 256 + t;
    int v = (i < N) ? (cnt[i] + 1) : 0;
    s[t] = v;
    __syncthreads();
    for (int off = 1; off < 256; off <<= 1) {
        int add = (t >= off) ? s[t - off] : 0;
        __syncthreads();
        s[t] += add;
        __syncthreads();
    }
    if (i < N) rp[i] = s[t] - v;
    if (t == 255) bsum[blockIdx.x] = s[255];
}

__global__ void k_scan2(int* __restrict__ bsum, int nb) {
    __shared__ int s[512];
    int t = threadIdx.x;
    int v = (t < nb) ? bsum[t] : 0;
    s[t] = v;
    __syncthreads();
    for (int off = 1; off < 512; off <<= 1) {
        int add = (t >= off) ? s[t - off] : 0;
        __syncthreads();
        s[t] += add;
        __syncthreads();
    }
    if (t < nb) bsum[t] = s[t] - v;
}

// finalize rp, place self-loop edge first in each row, cursor=1
__global__ void k_scan3(int* __restrict__ rp, const int* __restrict__ bsum,
                        int* __restrict__ cursor, const float* __restrict__ dinv,
                        int2* __restrict__ cw, int N, int Etot) {
    int i = blockIdx.x * blockDim.x + threadIdx.x;
    if (i < N) {
        int r = rp[i] + bsum[i >> 8];
        rp[i] = r;
        cursor[i] = 1;
        float d = dinv[i];
        int2 p;
        p.x = i;
        p.y = __float_as_int(OMA * d * d);
        cw[r] = p;
    }
    if (i == 0) rp[N] = Etot;
}

__global__ void k_place(const void* __restrict__ ei, int E,
                        const int* __restrict__ rp, int* __restrict__ cursor,
                        const float* __restrict__ dinv,
                        int2* __restrict__ cw, const int* __restrict__ flag) {
    int is64 = *flag;
    int e = blockIdx.x * blockDim.x + threadIdx.x;
    if (e < E) {
        int s = idx_at(ei, (size_t)e, is64);
        int d = idx_at(ei, (size_t)E + e, is64);
        int pos = rp[d] + atomicAdd(&cursor[d], 1);
        int2 p;
        p.x = s;
        p.y = __float_as_int(OMA * dinv[s] * dinv[d]);
        cw[pos] = p;
    }
}

// ---------------- GEMM: C[N][128] = act(A)[N][KTOT] @ B[KTOT][128] ----------------

template <int KTOT, bool RELU>
__global__ __launch_bounds__(256) void k_gemm(const float* __restrict__ A,
                                              const float* __restrict__ B,
                                              float* __restrict__ C, int N) {
    __shared__ float As[64][36];
    __shared__ float Bs[32][128];
    const int t  = threadIdx.x;
    const int tx = t & 15;
    const int ty = t >> 4;
    const int r0 = blockIdx.x * 64;

    float acc[4][8];
#pragma unroll
    for (int i = 0; i < 4; ++i)
#pragma unroll
        for (int j = 0; j < 8; ++j) acc[i][j] = 0.f;

    for (int k0 = 0; k0 < KTOT; k0 += 32) {
#pragma unroll
        for (int p = 0; p < 2; ++p) {
            int row = p * 32 + (t >> 3);
            int kk  = (t & 7) * 4;
            int gr  = r0 + row;
            float4 v = make_float4(0.f, 0.f, 0.f, 0.f);
            if (gr < N) v = *(const float4*)&A[(size_t)gr * KTOT + k0 + kk];
            if (RELU) {
                v.x = fmaxf(v.x, 0.f); v.y = fmaxf(v.y, 0.f);
                v.z = fmaxf(v.z, 0.f); v.w = fmaxf(v.w, 0.f);
            }
            *(float4*)&As[row][kk] = v;
        }
#pragma unroll
        for (int p = 0; p < 4; ++p) {
            int kr = p * 8 + (t >> 5);
            int c  = (t & 31) * 4;
            *(float4*)&Bs[kr][c] = *(const float4*)&B[(size_t)(k0 + kr) * Hd + c];
        }
        __syncthreads();
#pragma unroll
        for (int kk = 0; kk < 32; ++kk) {
            float a[4];
#pragma unroll
            for (int i = 0; i < 4; ++i) a[i] = As[ty * 4 + i][kk];
            float4 b0 = *(const float4*)&Bs[kk][tx * 8];
            float4 b1 = *(const float4*)&Bs[kk][tx * 8 + 4];
            float b[8] = {b0.x, b0.y, b0.z, b0.w, b1.x, b1.y, b1.z, b1.w};
#pragma unroll
            for (int i = 0; i < 4; ++i)
#pragma unroll
                for (int j = 0; j < 8; ++j) acc[i][j] = fmaf(a[i], b[j], acc[i][j]);
        }
        __syncthreads();
    }
#pragma unroll
    for (int i = 0; i < 4; ++i) {
        int gr = r0 + ty * 4 + i;
        if (gr < N) {
            *(float4*)&C[(size_t)gr * Hd + tx * 8]     = make_float4(acc[i][0], acc[i][1], acc[i][2], acc[i][3]);
            *(float4*)&C[(size_t)gr * Hd + tx * 8 + 4] = make_float4(acc[i][4], acc[i][5], acc[i][6], acc[i][7]);
        }
    }
}

// ---------------- propagation hop: zout = sum_e w_e * zin[src_e] + alpha*h ----------------
// wave-per-node; lane holds float2; 8-wide MLP unroll; self-loop already in CSR.

__global__ __launch_bounds__(256) void k_hop(const float* __restrict__ zin,
                                             const float* __restrict__ h,
                                             float* __restrict__ zout,
                                             const int* __restrict__ rp,
                                             const int2* __restrict__ cw, int N) {
    int wid  = (blockIdx.x * blockDim.x + threadIdx.x) >> 6;
    int lane = threadIdx.x & 63;
    if (wid >= N) return;
    const float2* zf = (const float2*)zin;

    int e   = __builtin_amdgcn_readfirstlane(rp[wid]);
    int end = __builtin_amdgcn_readfirstlane(rp[wid + 1]);

    float ax = 0.f, ay = 0.f, bx = 0.f, by = 0.f;

    for (; e + 8 <= end; e += 8) {
        int2 p0 = cw[e + 0], p1 = cw[e + 1], p2 = cw[e + 2], p3 = cw[e + 3];
        int2 p4 = cw[e + 4], p5 = cw[e + 5], p6 = cw[e + 6], p7 = cw[e + 7];
        float2 z0 = zf[((unsigned)p0.x << 6) + lane];
        float2 z1 = zf[((unsigned)p1.x << 6) + lane];
        float2 z2 = zf[((unsigned)p2.x << 6) + lane];
        float2 z3 = zf[((unsigned)p3.x << 6) + lane];
        float2 z4 = zf[((unsigned)p4.x << 6) + lane];
        float2 z5 = zf[((unsigned)p5.x << 6) + lane];
        float2 z6 = zf[((unsigned)p6.x << 6) + lane];
        float2 z7 = zf[((unsigned)p7.x << 6) + lane];
        float w0 = __int_as_float(p0.y), w1 = __int_as_float(p1.y);
        float w2 = __int_as_float(p2.y), w3 = __int_as_float(p3.y);
        float w4 = __int_as_float(p4.y), w5 = __int_as_float(p5.y);
        float w6 = __int_as_float(p6.y), w7 = __int_as_float(p7.y);
        ax = fmaf(w0, z0.x, ax); ay = fmaf(w0, z0.y, ay);
        bx = fmaf(w1, z1.x, bx); by = fmaf(w1, z1.y, by);
        ax = fmaf(w2, z2.x, ax); ay = fmaf(w2, z2.y, ay);
        bx = fmaf(w3, z3.x, bx); by = fmaf(w3, z3.y, by);
        ax = fmaf(w4, z4.x, ax); ay = fmaf(w4, z4.y, ay);
        bx = fmaf(w5, z5.x, bx); by = fmaf(w5, z5.y, by);
        ax = fmaf(w6, z6.x, ax); ay = fmaf(w6, z6.y, ay);
        bx = fmaf(w7, z7.x, bx); by = fmaf(w7, z7.y, by);
    }
    for (; e + 4 <= end; e += 4) {
        int2 p0 = cw[e + 0], p1 = cw[e + 1], p2 = cw[e + 2], p3 = cw[e + 3];
        float2 z0 = zf[((unsigned)p0.x << 6) + lane];
        float2 z1 = zf[((unsigned)p1.x << 6) + lane];
        float2 z2 = zf[((unsigned)p2.x << 6) + lane];
        float2 z3 = zf[((unsigned)p3.x << 6) + lane];
        float w0 = __int_as_float(p0.y), w1 = __int_as_float(p1.y);
        float w2 = __int_as_float(p2.y), w3 = __int_as_float(p3.y);
        ax = fmaf(w0, z0.x, ax); ay = fmaf(w0, z0.y, ay);
        bx = fmaf(w1, z1.x, bx); by = fmaf(w1, z1.y, by);
        ax = fmaf(w2, z2.x, ax); ay = fmaf(w2, z2.y, ay);
        bx = fmaf(w3, z3.x, bx); by = fmaf(w3, z3.y, by);
    }
    for (; e < end; ++e) {
        int2 p = cw[e];
        float2 zv = zf[((unsigned)p.x << 6) + lane];
        float wv = __int_as_float(p.y);
        ax = fmaf(wv, zv.x, ax); ay = fmaf(wv, zv.y, ay);
    }
    float2 hh = *(const float2*)&h[((size_t)wid << 7) + lane * 2];
    float2 o;
    o.x = ax + bx + A_ * hh.x;
    o.y = ay + by + A_ * hh.y;
    *(float2*)&zout[((size_t)wid << 7) + lane * 2] = o;
}

// ---------------- decode: out[j] = dot(z[e0[j]], z[e1[j]]) ----------------

__global__ __launch_bounds__(256) void k_decode(const float* __restrict__ z,
                                                const void* __restrict__ pos,
                                                const void* __restrict__ neg,
                                                float* __restrict__ out, int P, int Q,
                                                const int* __restrict__ flag) {
    int is64 = *flag;
    int t   = blockIdx.x * blockDim.x + threadIdx.x;
    int j   = t >> 4;
    int sub = t & 15;
    if (j >= P + Q) return;
    int a, b;
    if (j < P) { a = idx_at(pos, (size_t)j, is64); b = idx_at(pos, (size_t)P + j, is64); }
    else       { int jj = j - P; a = idx_at(neg, (size_t)jj, is64); b = idx_at(neg, (size_t)Q + jj, is64); }
    const float4* za = (const float4*)&z[(size_t)a * Hd];
    const float4* zb = (const float4*)&z[(size_t)b * Hd];
    float s = 0.f;
#pragma unroll
    for (int q = 0; q < 2; ++q) {
        float4 va = za[q * 16 + sub];
        float4 vb = zb[q * 16 + sub];
        s += va.x * vb.x + va.y * vb.y + va.z * vb.z + va.w * vb.w;
    }
#pragma unroll
    for (int off = 8; off >= 1; off >>= 1) s += __shfl_xor(s, off, 16);
    if (sub == 0) out[j] = s;
}

// ---------------- launch ----------------

extern "C" void kernel_launch(void* const* d_in, const int* in_sizes, int n_in,
                              void* d_out, int out_size, void* d_ws, size_t ws_size,
                              hipStream_t stream) {
    const float* x   = (const float*)d_in[0];
    const void*  ei  = d_in[1];
    const void*  pos = d_in[2];
    const void*  neg = d_in[3];
    const float* W1  = (const float*)d_in[4];
    const float* W2  = (const float*)d_in[5];
    float*       out = (float*)d_out;

    const int N = in_sizes[0] / Fin;
    const int E = in_sizes[1] / 2;
    const int P = in_sizes[2] / 2;
    const int Q = in_sizes[3] / 2;
    const int Etot = E + N;   // edges + self-loops

    char*  ws  = (char*)d_ws;
    size_t off = 0;
    auto carve = [&](size_t bytes) -> void* {
        void* p = ws + off;
        off = (off + bytes + 511) & ~(size_t)511;
        return p;
    };
    float* h      = (float*)carve((size_t)N * Hd * 4);
    float* zA     = (float*)carve((size_t)N * Hd * 4);
    float* zB     = (float*)carve((size_t)N * Hd * 4);
    float* dinv   = (float*)carve((size_t)N * 4);
    int*   cnt    = (int*)carve((size_t)N * 4);
    int*   rp     = (int*)carve((size_t)(N + 1) * 4);
    int*   cursor = (int*)carve((size_t)N * 4);
    int2*  cw     = (int2*)carve((size_t)Etot * 8);
    int    nb     = (N + 255) / 256;
    int*   bsum   = (int*)carve((size_t)nb * 4);
    int*   flag   = (int*)carve(4);
    (void)ws_size;

    const int gN = (N + 255) / 256;
    const int gE = (E + 255) / 256;

    // ---- dtype probe + build CSR (self-loops folded) + norms ----
    k_detect<<<1, 256, 0, stream>>>((const int*)ei, 4096, flag);
    k_zero_i32<<<gN, 256, 0, stream>>>(cnt, N);
    k_count<<<gE, 256, 0, stream>>>(ei, E, cnt, flag);
    k_dinv<<<gN, 256, 0, stream>>>(cnt, dinv, N);
    k_scan1<<<nb, 256, 0, stream>>>(cnt, rp, bsum, N);
    k_scan2<<<1, 512, 0, stream>>>(bsum, nb);
    k_scan3<<<gN, 256, 0, stream>>>(rp, bsum, cursor, dinv, cw, N, Etot);
    k_place<<<gE, 256, 0, stream>>>(ei, E, rp, cursor, dinv, cw, flag);

    const int gGemm = (N + 63) / 64;
    const int gHop  = (N * 64 + 255) / 256;

    // ---- layer 1: h = x @ W1; 10 hops ----
    k_gemm<Fin, false><<<gGemm, 256, 0, stream>>>(x, W1, h, N);
    {
        float* bufs[2] = {zA, zB};
        const float* zin = h;
        for (int k = 0; k < 10; ++k) {
            float* zout = bufs[k & 1];
            k_hop<<<gHop, 256, 0, stream>>>(zin, h, zout, rp, cw, N);
            zin = zout;
        }
    }
    // ---- layer 2: h = relu(zB) @ W2; 10 hops ----
    k_gemm<Hd, true><<<gGemm, 256, 0, stream>>>(zB, W2, h, N);
    {
        float* bufs[2] = {zA, zB};
        const float* zin = h;
        for (int k = 0; k < 10; ++k) {
            float* zout = bufs[k & 1];
            k_hop<<<gHop, 256, 0, stream>>>(zin, h, zout, rp, cw, N);
            zin = zout;
        }
    }
    // ---- decode ----
    const int gDec = ((P + Q) * 16 + 255) / 256;
    k_decode<<<gDec, 256, 0, stream>>>(zB, pos, neg, out, P, Q, flag);
}